// Round 1
// baseline (449.034 us; speedup 1.0000x reference)
//
#include <hip/hip_runtime.h>

#define D    64
#define NIT  8      // Gauss-Seidel sweeps: GS-8 residual <= Jacobi-16 < Jacobi-14 (old)
#define WPB  4      // waves per block; 1 wave = 1 batch, no cross-wave coupling

// Butcher coefficients
#define CA11 0.25f
#define CA12 -0.038675134594812866f   // 1/4 - sqrt(3)/6
#define CA21 0.5386751345948129f      // 1/4 + sqrt(3)/6
#define CA22 0.25f

// One wave per batch. Lane i owns row i of BOTH A1 and A2 (128 VGPRs).
// Zero __syncthreads: all LDS traffic is wave-private (intra-wave ordering via
// compiler-inserted lgkmcnt; wave_barrier pins scheduling).
__global__ __launch_bounds__(256, 3) void glrk_kernel(
    const float* __restrict__ A1, const float* __restrict__ A2,
    const float* __restrict__ y0, const float* __restrict__ hp,
    float* __restrict__ outy, float* __restrict__ oA1, float* __restrict__ oA2,
    int Btot)
{
    const int wave = threadIdx.x >> 6;
    const int lane = threadIdx.x & 63;
    const int b    = blockIdx.x * WPB + wave;
    if (b >= Btot) return;

    // Per-wave: 64x32-float col-half staging tile (8 KB), XOR-swizzled so both
    // the staging writes and the per-row b128 reads are bank-conflict-free
    // (old RS=68 pad left an 8-way conflict: stride 68 ≡ 4 banks/row).
    __shared__ float sT[WPB][D * 32];
    __shared__ float sV[WPB][2][D];

    const float  h    = *hp;
    const size_t moff = (size_t)b * (D * D);
    const float  y    = y0[(size_t)b * D + lane];

    float4 rowA[16], rowB[16];
    float* tile = sT[wave];

    // ---- Stage: coalesced 128-B global reads -> output copy -> swizzled LDS -> row regs.
    // Two column-half passes per matrix keep the tile at 8 KB so LDS never caps occupancy.
    auto stage = [&](const float* __restrict__ src, float* __restrict__ dst, float4* row) {
        const float4* s4 = (const float4*)(src + moff);
        float4*       d4 = (float4*)(dst + moff);
#pragma unroll
        for (int g = 0; g < 2; ++g) {
            float4 tmp[8];
#pragma unroll
            for (int j = 0; j < 8; ++j) {
                const int r  = j * 8 + (lane >> 3);           // 8 rows per inst
                const int i4 = r * 16 + 8 * g + (lane & 7);   // 128-B dense segments
                tmp[j] = s4[i4];
                d4[i4] = tmp[j];                              // fire-and-forget copy-out
            }
            // write: physical f4-group p = (logical c) ^ (row & 7)  -> conflict-free
            const int pw = ((lane & 7) ^ (lane >> 3)) * 4 + (lane >> 3) * 32;
#pragma unroll
            for (int j = 0; j < 8; ++j)
                *(float4*)&tile[pw + j * 256] = tmp[j];
            __builtin_amdgcn_wave_barrier();
            // read: lane i gathers its own row, undoing the swizzle -> conflict-free
#pragma unroll
            for (int c = 0; c < 8; ++c) {
                const int p = c ^ (lane & 7);
                row[8 * g + c] = *(const float4*)&tile[lane * 32 + p * 4];
            }
            __builtin_amdgcn_wave_barrier();   // tile reused by next pass / next matrix
        }
    };
    stage(A1, oA1, rowA);
    stage(A2, oA2, rowB);

    // ---- Gauss-Seidel fixed point, fully wave-internal (no barriers):
    //   v1 = y0 + h(a11 k1 + a12 k2);  k1 <- A1 v1   (k elements are lane-local)
    //   v2 = y0 + h(a21 k1' + a22 k2); k2 <- A2 v2   (uses the NEW k1)
    float k1 = 0.f, k2 = 0.f;
    float* v1 = sV[wave][0];
    float* v2 = sV[wave][1];
    const float4* v14 = (const float4*)v1;
    const float4* v24 = (const float4*)v2;

#pragma unroll 1
    for (int it = 0; it < NIT; ++it) {
        v1[lane] = fmaf(h, fmaf(CA11, k1, CA12 * k2), y);
        __builtin_amdgcn_wave_barrier();
        float a0 = 0.f, a1 = 0.f, a2 = 0.f, a3 = 0.f;
#pragma unroll
        for (int c = 0; c < 16; ++c) {        // vv[c]: uniform-address LDS broadcast
            const float4 u = v14[c];
            a0 = fmaf(rowA[c].x, u.x, a0);
            a1 = fmaf(rowA[c].y, u.y, a1);
            a2 = fmaf(rowA[c].z, u.z, a2);
            a3 = fmaf(rowA[c].w, u.w, a3);
        }
        k1 = (a0 + a1) + (a2 + a3);

        v2[lane] = fmaf(h, fmaf(CA21, k1, CA22 * k2), y);
        __builtin_amdgcn_wave_barrier();
        float b0 = 0.f, b1 = 0.f, b2 = 0.f, b3 = 0.f;
#pragma unroll
        for (int c = 0; c < 16; ++c) {
            const float4 u = v24[c];
            b0 = fmaf(rowB[c].x, u.x, b0);
            b1 = fmaf(rowB[c].y, u.y, b1);
            b2 = fmaf(rowB[c].z, u.z, b2);
            b3 = fmaf(rowB[c].w, u.w, b3);
        }
        k2 = (b0 + b1) + (b2 + b3);
    }

    outy[(size_t)b * D + lane] = fmaf(h, 0.5f * (k1 + k2), y);
}

extern "C" void kernel_launch(void* const* d_in, const int* in_sizes, int n_in,
                              void* d_out, int out_size, void* d_ws, size_t ws_size,
                              hipStream_t stream) {
    const float* A1 = (const float*)d_in[0];
    const float* A2 = (const float*)d_in[1];
    const float* y0 = (const float*)d_in[2];
    const float* hp = (const float*)d_in[3];

    const int B = in_sizes[2] / D;  // y0 is (B, D)

    float* outy = (float*)d_out;            // B*D
    float* oA1  = outy + (size_t)B * D;     // B*D*D
    float* oA2  = oA1 + (size_t)B * D * D;  // B*D*D

    const int grid = (B + WPB - 1) / WPB;
    glrk_kernel<<<grid, 64 * WPB, 0, stream>>>(A1, A2, y0, hp, outy, oA1, oA2, B);
}